// Round 18
// baseline (188.164 us; speedup 1.0000x reference)
//
#include <hip/hip_runtime.h>
#include <math.h>

#define NB 2
#define NL 256
#define DM 512
#define NH 8
#define DQ 64

typedef float v2f __attribute__((ext_vector_type(2)));

#if __has_builtin(__builtin_elementwise_fma)
__device__ __forceinline__ v2f fmav(v2f a, v2f b, v2f c) {
    return __builtin_elementwise_fma(a, b, c);
}
#else
__device__ __forceinline__ v2f fmav(v2f a, v2f b, v2f c) {
    v2f r; r.x = fmaf(a.x, b.x, c.x); r.y = fmaf(a.y, b.y, c.y); return r;
}
#endif
__device__ __forceinline__ v2f swapv(v2f a) {
    return __builtin_shufflevector(a, a, 1, 0);
}

// ---------------------------------------------------------------------------
// K1: QKV projection GEMM — 64x64 tile (R8-passed mappings), register
// double-buffered K-loop. grid (8,8,3) = 192 blocks <= 256 CUs: balanced
// 1 block/CU (the 32x64 config's 384 blocks left half the CUs doing 2).
// z==1 (k): TRANSPOSED (b,h,d,t). z==2 (v): u = (v+bias)@Win_h computed
// in-block; V staged transposed (pool[d][l]) so u-loop reads are b128.
// ---------------------------------------------------------------------------
__global__ __launch_bounds__(256) void qkv_gemm(
    const float* __restrict__ xq, const float* __restrict__ xk,
    const float* __restrict__ xv,
    const float* __restrict__ Wq, const float* __restrict__ Wk,
    const float* __restrict__ Wv,
    const float* __restrict__ bq, const float* __restrict__ bk,
    const float* __restrict__ bv,
    const float* __restrict__ Wre, const float* __restrict__ Wim,
    float* __restrict__ q, float* __restrict__ kT, float2* __restrict__ u)
{
    int z = blockIdx.z;
    const float* X = (z == 0) ? xq : (z == 1) ? xk : xv;
    const float* W = (z == 0) ? Wq : (z == 1) ? Wk : Wv;
    const float* bias = (z == 0) ? bq : (z == 1) ? bk : bv;

    // rows 0..31: A-tile [k][m]; rows 32..63: B-tile [k][n]; z==2 epilogue
    // reuses all 64 rows as V^T [d][l].
    __shared__ float pool[64][68];

    int tid = threadIdx.x;
    int tx = tid & 15, ty = tid >> 4;
    int m0 = blockIdx.y * 64, n0 = blockIdx.x * 64;

    // A staging: lane = m, wave = k-quad (R8-passed, conflict-free)
    int am = tid & 63, kq = tid >> 6;
    const float* Aptr = X + (m0 + am) * 512 + kq * 4;
    // B staging: row-major b128
    int br = tid >> 4, bc4 = (tid & 15) * 4;
    const float* Bptr0 = W + br * 512 + n0 + bc4;
    const float* Bptr1 = W + (br + 16) * 512 + n0 + bc4;

    float acc[4][4] = {};

    float4 aR0 = *(const float4*)(Aptr);
    float4 aR1 = *(const float4*)(Aptr + 16);
    float4 bR0 = *(const float4*)(Bptr0);
    float4 bR1 = *(const float4*)(Bptr1);

    for (int k0 = 0; k0 < 512; k0 += 32) {
        pool[kq * 4 + 0][am] = aR0.x; pool[kq * 4 + 1][am] = aR0.y;
        pool[kq * 4 + 2][am] = aR0.z; pool[kq * 4 + 3][am] = aR0.w;
        pool[kq * 4 + 16][am] = aR1.x; pool[kq * 4 + 17][am] = aR1.y;
        pool[kq * 4 + 18][am] = aR1.z; pool[kq * 4 + 19][am] = aR1.w;
        *(float4*)&pool[32 + br][bc4] = bR0;
        *(float4*)&pool[32 + br + 16][bc4] = bR1;
        __syncthreads();

        if (k0 + 32 < 512) {
            aR0 = *(const float4*)(Aptr + k0 + 32);
            aR1 = *(const float4*)(Aptr + k0 + 48);
            bR0 = *(const float4*)(Bptr0 + (k0 + 32) * 512);
            bR1 = *(const float4*)(Bptr1 + (k0 + 32) * 512);
        }

        #pragma unroll
        for (int kk = 0; kk < 32; kk++) {
            float4 a = *(const float4*)&pool[kk][ty * 4];
            float4 bb = *(const float4*)&pool[32 + kk][tx * 4];
            acc[0][0] += a.x * bb.x; acc[0][1] += a.x * bb.y;
            acc[0][2] += a.x * bb.z; acc[0][3] += a.x * bb.w;
            acc[1][0] += a.y * bb.x; acc[1][1] += a.y * bb.y;
            acc[1][2] += a.y * bb.z; acc[1][3] += a.y * bb.w;
            acc[2][0] += a.z * bb.x; acc[2][1] += a.z * bb.y;
            acc[2][2] += a.z * bb.z; acc[2][3] += a.z * bb.w;
            acc[3][0] += a.w * bb.x; acc[3][1] += a.w * bb.y;
            acc[3][2] += a.w * bb.z; acc[3][3] += a.w * bb.w;
        }
        __syncthreads();
    }

    if (z < 2) {
        float* O = (z == 0) ? q : kT;
        #pragma unroll
        for (int i = 0; i < 4; i++) {
            int m = m0 + ty * 4 + i;
            int b = m >> 8, l = m & 255;
            #pragma unroll
            for (int j = 0; j < 4; j++) {
                int n = n0 + tx * 4 + j;
                int h = n >> 6, d = n & 63;
                float val = acc[i][j] + bias[n];
                if (z == 1)
                    O[((b * NH + h) * DQ + d) * NL + l] = val;   // kT
                else
                    O[((b * NH + h) * NL + l) * DQ + d] = val;
            }
        }
    } else {
        // ---- fused u. Stage V TRANSPOSED: pool[d][l], d = n-col, l = m-row.
        int h = blockIdx.x;            // n-tile == head
        int b = m0 >> 8;
        #pragma unroll
        for (int i = 0; i < 4; i++)
            #pragma unroll
            for (int j = 0; j < 4; j++)
                pool[tx * 4 + j][ty * 4 + i] = acc[i][j] + bias[n0 + tx * 4 + j];
        __syncthreads();

        // thread: rows l = ty*4..+3, cols e = tx*4..+3
        float ur[4][4] = {}, ui[4][4] = {};
        const float* wr = Wre + h * 4096 + tx * 4;
        const float* wi = Wim + h * 4096 + tx * 4;
        #pragma unroll 4
        for (int d = 0; d < 64; d++) {
            float4 vv = *(const float4*)&pool[d][ty * 4];   // V[l][d], l=ty*4..+3
            float4 wre = *(const float4*)(wr + d * 64);
            float4 wim = *(const float4*)(wi + d * 64);
            #pragma unroll
            for (int i = 0; i < 4; i++) {
                float v = (i == 0) ? vv.x : (i == 1) ? vv.y : (i == 2) ? vv.z : vv.w;
                ur[i][0] += v * wre.x; ur[i][1] += v * wre.y;
                ur[i][2] += v * wre.z; ur[i][3] += v * wre.w;
                ui[i][0] += v * wim.x; ui[i][1] += v * wim.y;
                ui[i][2] += v * wim.z; ui[i][3] += v * wim.w;
            }
        }
        #pragma unroll
        for (int i = 0; i < 4; i++) {
            int l = (m0 & 255) + ty * 4 + i;
            float2* up = u + ((size_t)(b * NH + h) * NL + l) * DQ + tx * 4;
            #pragma unroll
            for (int j = 0; j < 4; j++)
                up[j] = make_float2(ur[i][j], ui[i][j]);
        }
    }
}

// ---------------------------------------------------------------------------
// K2: attn softmax prologue + EUNN recurrence (R17-passed packed-FP32 body).
// Only change: arow stride 256 -> 257 (kills the 524k/dispatch LDS bank
// conflicts; the two per-wave rows now live in adjacent banks).
// ---------------------------------------------------------------------------
__device__ __forceinline__ float rot_up2(float x) {   // lane i <- lane (i+2)%64
    int v = __builtin_amdgcn_mov_dpp(__float_as_int(x), 0x134, 0xF, 0xF, true);
    v = __builtin_amdgcn_mov_dpp(v, 0x134, 0xF, 0xF, true);
    return __int_as_float(v);
}
__device__ __forceinline__ float rot_dn2(float x) {   // lane i <- lane (i-2)%64
    int v = __builtin_amdgcn_mov_dpp(__float_as_int(x), 0x13C, 0xF, 0xF, true);
    v = __builtin_amdgcn_mov_dpp(v, 0x13C, 0xF, 0xF, true);
    return __int_as_float(v);
}

__global__ __launch_bounds__(256) void rnn_kernel(
    const float* __restrict__ q, const float* __restrict__ kT,
    const float* __restrict__ mask, float* __restrict__ attn_o,
    const float2* __restrict__ u,
    const float* __restrict__ theta, const float* __restrict__ phi,
    const float* __restrict__ rnn_bias, float* __restrict__ rnn_out)
{
    int tid = threadIdx.x;
    int wv = tid >> 6;
    int lane = tid & 63;

    int qg = blockIdx.x & 31;
    int h  = (blockIdx.x >> 5) & 7;
    int b  = blockIdx.x >> 8;

    __shared__ float sp[2608];       // qs[512] | lg[8*260] | redm[8] | reds[8]
    __shared__ float arow[8 * 257];  // stride 257: conflict-free paired reads

    // ================= attn prologue =================
    {
        float* qs   = sp;
        float* lg   = sp + 512;
        float* redm = sp + 512 + 2080;
        float* reds = redm + 8;

        ((float2*)qs)[tid] =
            ((const float2*)(q + ((size_t)(b * NH + h) * NL + qg * 8) * DQ))[tid];
        __syncthreads();

        const float* kp = kT + (size_t)((b * NH + h) * DQ) * NL + tid;
        float acc[8] = {};
        #pragma unroll
        for (int d4 = 0; d4 < 16; d4++) {
            float kv0 = kp[(d4 * 4 + 0) * NL];
            float kv1 = kp[(d4 * 4 + 1) * NL];
            float kv2 = kp[(d4 * 4 + 2) * NL];
            float kv3 = kp[(d4 * 4 + 3) * NL];
            #pragma unroll
            for (int j = 0; j < 8; j++) {
                const float4 qv = *(const float4*)&qs[j * 64 + d4 * 4];
                acc[j] += qv.x * kv0 + qv.y * kv1 + qv.z * kv2 + qv.w * kv3;
            }
        }
        #pragma unroll
        for (int j = 0; j < 8; j++) {
            float mv = mask[(size_t)(b * NL + qg * 8 + j) * NL + tid];
            acc[j] = acc[j] * 0.125f - ((mv == 1.0f) ? INFINITY : mv);
            lg[j * 260 + tid] = acc[j];
        }
        __syncthreads();
        #pragma unroll
        for (int jj = 0; jj < 2; jj++) {
            int j = wv * 2 + jj;
            float v0 = lg[j * 260 + lane],       v1 = lg[j * 260 + 64 + lane];
            float v2 = lg[j * 260 + 128 + lane], v3 = lg[j * 260 + 192 + lane];
            float mx = fmaxf(fmaxf(v0, v1), fmaxf(v2, v3));
            #pragma unroll
            for (int o = 32; o; o >>= 1) mx = fmaxf(mx, __shfl_xor(mx, o, 64));
            float s = __expf(v0 - mx) + __expf(v1 - mx) +
                      __expf(v2 - mx) + __expf(v3 - mx);
            #pragma unroll
            for (int o = 32; o; o >>= 1) s += __shfl_xor(s, o, 64);
            if (lane == 0) { redm[j] = mx; reds[j] = s; }
        }
        __syncthreads();
        #pragma unroll
        for (int j = 0; j < 8; j++) {
            float p = __expf(acc[j] - redm[j]) * __builtin_amdgcn_rcpf(reds[j]);
            attn_o[((size_t)(b * NH + h) * NL + qg * 8 + j) * NL + tid] = p;
            arow[j * 257 + tid] = p;
        }
        __syncthreads();
    }

    // ================= EUNN recurrence (packed-FP32) =================
    int par = lane & 1;
    int p = lane >> 1;
    int rec = blockIdx.x * 8 + wv * 2 + par;
    int qi = rec & 255;

    const float* tb = theta + h * 64;
    const float* pb = phi + h * 64;

    float th0 = tb[p], ph0 = pb[p];
    float c0 = cosf(th0), s0 = sinf(th0);
    float cp0 = cosf(ph0), sp0 = sinf(ph0);
    float W0ar = -s0 * cp0, W0ai = -s0 * sp0;
    float W0br =  s0 * cp0, W0bi = -s0 * sp0;

    float th1 = tb[32 + p], ph1 = pb[32 + p];
    float c1 = cosf(th1), s1 = sinf(th1);
    float W1ar = -s1 * cosf(ph1), W1ai = -s1 * sinf(ph1);

    int pm = (p + 31) & 31;
    float th1m = tb[32 + pm], ph1m = pb[32 + pm];
    float c1m = cosf(th1m), s1m = sinf(th1m);
    float W1br = s1m * cosf(ph1m), W1bi = -s1m * sinf(ph1m);

    float bias0 = rnn_bias[h * 64 + 2 * p];
    float bias1 = rnn_bias[h * 64 + 2 * p + 1];

    v2f c0v  = {c0, c0},   c1v  = {c1, c1},   c1mv = {c1m, c1m};
    v2f W0arV = {W0ar, W0ar}, W0aiN = {-W0ai, W0ai};
    v2f W0brV = {W0br, W0br}, W0biN = {-W0bi, W0bi};
    v2f W1arV = {W1ar, W1ar}, W1aiN = {-W1ai, W1ai};
    v2f W1brV = {W1br, W1br}, W1biN = {-W1bi, W1bi};

    const float* arc = arow + (wv * 2 + par) * 257;
    const float4* up4 = (const float4*)(u + (size_t)((b * NH + h) * NL) * DQ) + p;

    v2f e0 = {0.f, 0.f}, e1 = {0.f, 0.f};
    #pragma unroll 8
    for (int t = 0; t < 256; t++) {
        float4 uu = up4[t * 32];
        float a_t = arc[t];
        v2f atv = {a_t, a_t};
        v2f u0 = {uu.x, uu.y}, u1 = {uu.z, uu.w};

        v2f na = fmav(c0v, e0, fmav(W0arV, e1, W0aiN * swapv(e1)));
        v2f nb = fmav(c0v, e1, fmav(W0brV, e0, W0biN * swapv(e0)));

        v2f f1, f2;
        f1.x = rot_up2(na.x); f1.y = rot_up2(na.y);
        f2.x = rot_dn2(nb.x); f2.y = rot_dn2(nb.y);

        v2f z1 = fmav(c1v, nb, fmav(W1arV, f1, fmav(W1aiN, swapv(f1), atv * u1)));
        v2f z0 = fmav(c1mv, na, fmav(W1brV, f2, fmav(W1biN, swapv(f2), atv * u0)));

        // modrelu — exact reference form (R7 lesson: no rsqrt fold)
        float mm0 = z0.x * z0.x + z0.y * z0.y;
        float m0 = __builtin_amdgcn_sqrtf(mm0);
        float sc0 = fmaxf(m0 + bias0, 0.f) * __builtin_amdgcn_rcpf(m0 + 1e-5f);
        v2f sc0v = {sc0, sc0};
        e0 = z0 * sc0v;

        float mm1 = z1.x * z1.x + z1.y * z1.y;
        float m1 = __builtin_amdgcn_sqrtf(mm1);
        float sc1 = fmaxf(m1 + bias1, 0.f) * __builtin_amdgcn_rcpf(m1 + 1e-5f);
        v2f sc1v = {sc1, sc1};
        e1 = z1 * sc1v;
    }

    float2 o = make_float2(e0.x, e1.x);
    *(float2*)&rnn_out[(size_t)(b * NL + qi) * DM + h * DQ + 2 * p] = o;
}

// ---------------------------------------------------------------------------
// K3: output projection (R16/R17-passed, unchanged). Register double-buffered.
// ---------------------------------------------------------------------------
__global__ __launch_bounds__(256) void out_gemm(
    const float* __restrict__ A, const float* __restrict__ W,
    const float* __restrict__ bias, float* __restrict__ C)
{
    __shared__ float As[32][17];
    __shared__ float Bs[32][68];

    int tid = threadIdx.x;
    int tx = tid & 15, ty = tid >> 4;
    int m0 = blockIdx.y * 16, n0 = blockIdx.x * 64;

    int ar = tid >> 4, ac2 = (tid & 15) * 2;
    int br = tid >> 4, bc4 = (tid & 15) * 4;
    const float* Aptr = A + (m0 + ar) * 512 + ac2;
    const float* Bptr0 = W + br * 512 + n0 + bc4;
    const float* Bptr1 = W + (br + 16) * 512 + n0 + bc4;

    float acc[4] = {};

    float2 aR = *(const float2*)(Aptr);
    float4 bR0 = *(const float4*)(Bptr0);
    float4 bR1 = *(const float4*)(Bptr1);

    for (int k0 = 0; k0 < 512; k0 += 32) {
        As[ac2 + 0][ar] = aR.x; As[ac2 + 1][ar] = aR.y;
        *(float4*)&Bs[br][bc4] = bR0;
        *(float4*)&Bs[br + 16][bc4] = bR1;
        __syncthreads();

        if (k0 + 32 < 512) {
            aR  = *(const float2*)(Aptr + k0 + 32);
            bR0 = *(const float4*)(Bptr0 + (k0 + 32) * 512);
            bR1 = *(const float4*)(Bptr1 + (k0 + 32) * 512);
        }

        #pragma unroll
        for (int kk = 0; kk < 32; kk++) {
            float a = As[kk][ty];
            float4 bb = *(const float4*)&Bs[kk][tx * 4];
            acc[0] += a * bb.x; acc[1] += a * bb.y;
            acc[2] += a * bb.z; acc[3] += a * bb.w;
        }
        __syncthreads();
    }

    int m = m0 + ty;
    #pragma unroll
    for (int j = 0; j < 4; j++) {
        int n = n0 + tx * 4 + j;
        C[m * 512 + n] = acc[j] + bias[n];
    }
}

// ---------------------------------------------------------------------------
extern "C" void kernel_launch(void* const* d_in, const int* in_sizes, int n_in,
                              void* d_out, int out_size, void* d_ws, size_t ws_size,
                              hipStream_t stream)
{
    const float* x_q  = (const float*)d_in[0];
    const float* x_k  = (const float*)d_in[1];
    const float* x_v  = (const float*)d_in[2];
    const float* mask = (const float*)d_in[3];
    const float* Wq   = (const float*)d_in[4];
    const float* bq   = (const float*)d_in[5];
    const float* Wk   = (const float*)d_in[6];
    const float* bk   = (const float*)d_in[7];
    const float* Wv   = (const float*)d_in[8];
    const float* bv   = (const float*)d_in[9];
    const float* Wo   = (const float*)d_in[10];
    const float* bo   = (const float*)d_in[11];
    const float* theta= (const float*)d_in[12];
    const float* phi  = (const float*)d_in[13];
    const float* Wre  = (const float*)d_in[14];
    const float* Wim  = (const float*)d_in[15];
    const float* rb   = (const float*)d_in[16];

    float* ws = (float*)d_ws;
    float*  q_ws    = ws;                       // 262144 f
    float*  kT_ws   = ws + 262144;              // 262144 f (b,h,d,t)
    float2* u_ws    = (float2*)(ws + 524288);   // 262144 float2
    float*  rnn_o   = ws + 1048576;             // 262144 f

    float* out_o  = (float*)d_out;              // (2,256,512)
    float* attn_o = out_o + NB * NL * DM;       // (2,8,256,256)

    qkv_gemm<<<dim3(8, 8, 3), 256, 0, stream>>>(
        x_q, x_k, x_v, Wq, Wk, Wv, bq, bk, bv, Wre, Wim,
        q_ws, kT_ws, u_ws);

    rnn_kernel<<<dim3(512), 256, 0, stream>>>(
        q_ws, kT_ws, mask, attn_o, u_ws, theta, phi, rb, rnn_o);

    out_gemm<<<dim3(8, 32), 256, 0, stream>>>(rnn_o, Wo, bo, out_o);
}

// Round 19
// 186.831 us; speedup vs baseline: 1.0071x; 1.0071x over previous
//
#include <hip/hip_runtime.h>
#include <math.h>

#define NB 2
#define NL 256
#define DM 512
#define NH 8
#define DQ 64

typedef float v2f __attribute__((ext_vector_type(2)));

#if __has_builtin(__builtin_elementwise_fma)
__device__ __forceinline__ v2f fmav(v2f a, v2f b, v2f c) {
    return __builtin_elementwise_fma(a, b, c);
}
#else
__device__ __forceinline__ v2f fmav(v2f a, v2f b, v2f c) {
    v2f r; r.x = fmaf(a.x, b.x, c.x); r.y = fmaf(a.y, b.y, c.y); return r;
}
#endif
__device__ __forceinline__ v2f swapv(v2f a) {
    return __builtin_shufflevector(a, a, 1, 0);
}

// ---------------------------------------------------------------------------
// K1: QKV projection GEMM — R17-PASSED config restored: 32x64 tile, 384
// blocks (the 64x64/192-block variant left 64 CUs idle and regressed).
// Register double-buffered K-loop. z==1 (k): TRANSPOSED (b,h,d,t).
// z==2 (v): u = (v+bias)@Win_h computed in-block.
// ---------------------------------------------------------------------------
__global__ __launch_bounds__(256) void qkv_gemm(
    const float* __restrict__ xq, const float* __restrict__ xk,
    const float* __restrict__ xv,
    const float* __restrict__ Wq, const float* __restrict__ Wk,
    const float* __restrict__ Wv,
    const float* __restrict__ bq, const float* __restrict__ bk,
    const float* __restrict__ bv,
    const float* __restrict__ Wre, const float* __restrict__ Wim,
    float* __restrict__ q, float* __restrict__ kT, float2* __restrict__ u)
{
    int z = blockIdx.z;
    const float* X = (z == 0) ? xq : (z == 1) ? xk : xv;
    const float* W = (z == 0) ? Wq : (z == 1) ? Wk : Wv;
    const float* bias = (z == 0) ? bq : (z == 1) ? bk : bv;

    __shared__ float As[32][33];
    __shared__ float Bs[32][68];

    int tid = threadIdx.x;
    int tx = tid & 15, ty = tid >> 4;
    int m0 = blockIdx.y * 32, n0 = blockIdx.x * 64;

    int ar = tid >> 3, ac4 = (tid & 7) * 4;
    int br = tid >> 4, bc4 = (tid & 15) * 4;
    const float* Aptr = X + (m0 + ar) * 512 + ac4;
    const float* Bptr0 = W + br * 512 + n0 + bc4;
    const float* Bptr1 = W + (br + 16) * 512 + n0 + bc4;

    float acc[2][4] = {};

    float4 aR = *(const float4*)(Aptr);
    float4 bR0 = *(const float4*)(Bptr0);
    float4 bR1 = *(const float4*)(Bptr1);

    for (int k0 = 0; k0 < 512; k0 += 32) {
        As[ac4 + 0][ar] = aR.x; As[ac4 + 1][ar] = aR.y;
        As[ac4 + 2][ar] = aR.z; As[ac4 + 3][ar] = aR.w;
        *(float4*)&Bs[br][bc4] = bR0;
        *(float4*)&Bs[br + 16][bc4] = bR1;
        __syncthreads();

        if (k0 + 32 < 512) {
            aR  = *(const float4*)(Aptr + k0 + 32);
            bR0 = *(const float4*)(Bptr0 + (k0 + 32) * 512);
            bR1 = *(const float4*)(Bptr1 + (k0 + 32) * 512);
        }

        #pragma unroll
        for (int kk = 0; kk < 32; kk++) {
            float a0 = As[kk][ty * 2 + 0];
            float a1 = As[kk][ty * 2 + 1];
            float4 bb = *(const float4*)&Bs[kk][tx * 4];
            acc[0][0] += a0 * bb.x; acc[0][1] += a0 * bb.y;
            acc[0][2] += a0 * bb.z; acc[0][3] += a0 * bb.w;
            acc[1][0] += a1 * bb.x; acc[1][1] += a1 * bb.y;
            acc[1][2] += a1 * bb.z; acc[1][3] += a1 * bb.w;
        }
        __syncthreads();
    }

    if (z < 2) {
        float* O = (z == 0) ? q : kT;
        #pragma unroll
        for (int i = 0; i < 2; i++) {
            int m = m0 + ty * 2 + i;
            int b = m >> 8, l = m & 255;
            #pragma unroll
            for (int j = 0; j < 4; j++) {
                int n = n0 + tx * 4 + j;
                int h = n >> 6, d = n & 63;
                float val = acc[i][j] + bias[n];
                if (z == 1)
                    O[((b * NH + h) * DQ + d) * NL + l] = val;   // kT
                else
                    O[((b * NH + h) * NL + l) * DQ + d] = val;
            }
        }
    } else {
        int h = blockIdx.x;            // n-tile == head
        int b = m0 >> 8;
        #pragma unroll
        for (int i = 0; i < 2; i++)
            #pragma unroll
            for (int j = 0; j < 4; j++)
                Bs[ty * 2 + i][tx * 4 + j] = acc[i][j] + bias[n0 + tx * 4 + j];
        __syncthreads();

        int r0 = ty * 2, c4 = tx * 4;
        float ur[2][4] = {}, ui[2][4] = {};
        const float* wr = Wre + h * 4096 + c4;
        const float* wi = Wim + h * 4096 + c4;
        #pragma unroll 4
        for (int d = 0; d < 64; d++) {
            float v0 = Bs[r0][d];
            float v1 = Bs[r0 + 1][d];
            float4 wre = *(const float4*)(wr + d * 64);
            float4 wim = *(const float4*)(wi + d * 64);
            ur[0][0] += v0 * wre.x; ur[0][1] += v0 * wre.y;
            ur[0][2] += v0 * wre.z; ur[0][3] += v0 * wre.w;
            ui[0][0] += v0 * wim.x; ui[0][1] += v0 * wim.y;
            ui[0][2] += v0 * wim.z; ui[0][3] += v0 * wim.w;
            ur[1][0] += v1 * wre.x; ur[1][1] += v1 * wre.y;
            ur[1][2] += v1 * wre.z; ur[1][3] += v1 * wre.w;
            ui[1][0] += v1 * wim.x; ui[1][1] += v1 * wim.y;
            ui[1][2] += v1 * wim.z; ui[1][3] += v1 * wim.w;
        }
        #pragma unroll
        for (int i = 0; i < 2; i++) {
            int l = (m0 & 255) + r0 + i;
            float2* up = u + ((size_t)(b * NH + h) * NL + l) * DQ + c4;
            #pragma unroll
            for (int j = 0; j < 4; j++)
                up[j] = make_float2(ur[i][j], ui[i][j]);
        }
    }
}

// ---------------------------------------------------------------------------
// K2: attn softmax prologue + EUNN recurrence (R18-passed: packed-FP32 core,
// conflict-free arow stride 257).
// ---------------------------------------------------------------------------
__device__ __forceinline__ float rot_up2(float x) {   // lane i <- lane (i+2)%64
    int v = __builtin_amdgcn_mov_dpp(__float_as_int(x), 0x134, 0xF, 0xF, true);
    v = __builtin_amdgcn_mov_dpp(v, 0x134, 0xF, 0xF, true);
    return __int_as_float(v);
}
__device__ __forceinline__ float rot_dn2(float x) {   // lane i <- lane (i-2)%64
    int v = __builtin_amdgcn_mov_dpp(__float_as_int(x), 0x13C, 0xF, 0xF, true);
    v = __builtin_amdgcn_mov_dpp(v, 0x13C, 0xF, 0xF, true);
    return __int_as_float(v);
}

__global__ __launch_bounds__(256) void rnn_kernel(
    const float* __restrict__ q, const float* __restrict__ kT,
    const float* __restrict__ mask, float* __restrict__ attn_o,
    const float2* __restrict__ u,
    const float* __restrict__ theta, const float* __restrict__ phi,
    const float* __restrict__ rnn_bias, float* __restrict__ rnn_out)
{
    int tid = threadIdx.x;
    int wv = tid >> 6;
    int lane = tid & 63;

    int qg = blockIdx.x & 31;
    int h  = (blockIdx.x >> 5) & 7;
    int b  = blockIdx.x >> 8;

    __shared__ float sp[2608];       // qs[512] | lg[8*260] | redm[8] | reds[8]
    __shared__ float arow[8 * 257];  // stride 257: conflict-free paired reads

    // ================= attn prologue =================
    {
        float* qs   = sp;
        float* lg   = sp + 512;
        float* redm = sp + 512 + 2080;
        float* reds = redm + 8;

        ((float2*)qs)[tid] =
            ((const float2*)(q + ((size_t)(b * NH + h) * NL + qg * 8) * DQ))[tid];
        __syncthreads();

        const float* kp = kT + (size_t)((b * NH + h) * DQ) * NL + tid;
        float acc[8] = {};
        #pragma unroll
        for (int d4 = 0; d4 < 16; d4++) {
            float kv0 = kp[(d4 * 4 + 0) * NL];
            float kv1 = kp[(d4 * 4 + 1) * NL];
            float kv2 = kp[(d4 * 4 + 2) * NL];
            float kv3 = kp[(d4 * 4 + 3) * NL];
            #pragma unroll
            for (int j = 0; j < 8; j++) {
                const float4 qv = *(const float4*)&qs[j * 64 + d4 * 4];
                acc[j] += qv.x * kv0 + qv.y * kv1 + qv.z * kv2 + qv.w * kv3;
            }
        }
        #pragma unroll
        for (int j = 0; j < 8; j++) {
            float mv = mask[(size_t)(b * NL + qg * 8 + j) * NL + tid];
            acc[j] = acc[j] * 0.125f - ((mv == 1.0f) ? INFINITY : mv);
            lg[j * 260 + tid] = acc[j];
        }
        __syncthreads();
        #pragma unroll
        for (int jj = 0; jj < 2; jj++) {
            int j = wv * 2 + jj;
            float v0 = lg[j * 260 + lane],       v1 = lg[j * 260 + 64 + lane];
            float v2 = lg[j * 260 + 128 + lane], v3 = lg[j * 260 + 192 + lane];
            float mx = fmaxf(fmaxf(v0, v1), fmaxf(v2, v3));
            #pragma unroll
            for (int o = 32; o; o >>= 1) mx = fmaxf(mx, __shfl_xor(mx, o, 64));
            float s = __expf(v0 - mx) + __expf(v1 - mx) +
                      __expf(v2 - mx) + __expf(v3 - mx);
            #pragma unroll
            for (int o = 32; o; o >>= 1) s += __shfl_xor(s, o, 64);
            if (lane == 0) { redm[j] = mx; reds[j] = s; }
        }
        __syncthreads();
        #pragma unroll
        for (int j = 0; j < 8; j++) {
            float p = __expf(acc[j] - redm[j]) * __builtin_amdgcn_rcpf(reds[j]);
            attn_o[((size_t)(b * NH + h) * NL + qg * 8 + j) * NL + tid] = p;
            arow[j * 257 + tid] = p;
        }
        __syncthreads();
    }

    // ================= EUNN recurrence (packed-FP32) =================
    int par = lane & 1;
    int p = lane >> 1;
    int rec = blockIdx.x * 8 + wv * 2 + par;
    int qi = rec & 255;

    const float* tb = theta + h * 64;
    const float* pb = phi + h * 64;

    float th0 = tb[p], ph0 = pb[p];
    float c0 = cosf(th0), s0 = sinf(th0);
    float cp0 = cosf(ph0), sp0 = sinf(ph0);
    float W0ar = -s0 * cp0, W0ai = -s0 * sp0;
    float W0br =  s0 * cp0, W0bi = -s0 * sp0;

    float th1 = tb[32 + p], ph1 = pb[32 + p];
    float c1 = cosf(th1), s1 = sinf(th1);
    float W1ar = -s1 * cosf(ph1), W1ai = -s1 * sinf(ph1);

    int pm = (p + 31) & 31;
    float th1m = tb[32 + pm], ph1m = pb[32 + pm];
    float c1m = cosf(th1m), s1m = sinf(th1m);
    float W1br = s1m * cosf(ph1m), W1bi = -s1m * sinf(ph1m);

    float bias0 = rnn_bias[h * 64 + 2 * p];
    float bias1 = rnn_bias[h * 64 + 2 * p + 1];

    v2f c0v  = {c0, c0},   c1v  = {c1, c1},   c1mv = {c1m, c1m};
    v2f W0arV = {W0ar, W0ar}, W0aiN = {-W0ai, W0ai};
    v2f W0brV = {W0br, W0br}, W0biN = {-W0bi, W0bi};
    v2f W1arV = {W1ar, W1ar}, W1aiN = {-W1ai, W1ai};
    v2f W1brV = {W1br, W1br}, W1biN = {-W1bi, W1bi};

    const float* arc = arow + (wv * 2 + par) * 257;
    const float4* up4 = (const float4*)(u + (size_t)((b * NH + h) * NL) * DQ) + p;

    v2f e0 = {0.f, 0.f}, e1 = {0.f, 0.f};
    #pragma unroll 8
    for (int t = 0; t < 256; t++) {
        float4 uu = up4[t * 32];
        float a_t = arc[t];
        v2f atv = {a_t, a_t};
        v2f u0 = {uu.x, uu.y}, u1 = {uu.z, uu.w};

        v2f na = fmav(c0v, e0, fmav(W0arV, e1, W0aiN * swapv(e1)));
        v2f nb = fmav(c0v, e1, fmav(W0brV, e0, W0biN * swapv(e0)));

        v2f f1, f2;
        f1.x = rot_up2(na.x); f1.y = rot_up2(na.y);
        f2.x = rot_dn2(nb.x); f2.y = rot_dn2(nb.y);

        v2f z1 = fmav(c1v, nb, fmav(W1arV, f1, fmav(W1aiN, swapv(f1), atv * u1)));
        v2f z0 = fmav(c1mv, na, fmav(W1brV, f2, fmav(W1biN, swapv(f2), atv * u0)));

        // modrelu — exact reference form (R7 lesson: no rsqrt fold)
        float mm0 = z0.x * z0.x + z0.y * z0.y;
        float m0 = __builtin_amdgcn_sqrtf(mm0);
        float sc0 = fmaxf(m0 + bias0, 0.f) * __builtin_amdgcn_rcpf(m0 + 1e-5f);
        v2f sc0v = {sc0, sc0};
        e0 = z0 * sc0v;

        float mm1 = z1.x * z1.x + z1.y * z1.y;
        float m1 = __builtin_amdgcn_sqrtf(mm1);
        float sc1 = fmaxf(m1 + bias1, 0.f) * __builtin_amdgcn_rcpf(m1 + 1e-5f);
        v2f sc1v = {sc1, sc1};
        e1 = z1 * sc1v;
    }

    float2 o = make_float2(e0.x, e1.x);
    *(float2*)&rnn_out[(size_t)(b * NL + qi) * DM + h * DQ + 2 * p] = o;
}

// ---------------------------------------------------------------------------
// K3: output projection (R16/R17-passed, unchanged). Register double-buffered.
// ---------------------------------------------------------------------------
__global__ __launch_bounds__(256) void out_gemm(
    const float* __restrict__ A, const float* __restrict__ W,
    const float* __restrict__ bias, float* __restrict__ C)
{
    __shared__ float As[32][17];
    __shared__ float Bs[32][68];

    int tid = threadIdx.x;
    int tx = tid & 15, ty = tid >> 4;
    int m0 = blockIdx.y * 16, n0 = blockIdx.x * 64;

    int ar = tid >> 4, ac2 = (tid & 15) * 2;
    int br = tid >> 4, bc4 = (tid & 15) * 4;
    const float* Aptr = A + (m0 + ar) * 512 + ac2;
    const float* Bptr0 = W + br * 512 + n0 + bc4;
    const float* Bptr1 = W + (br + 16) * 512 + n0 + bc4;

    float acc[4] = {};

    float2 aR = *(const float2*)(Aptr);
    float4 bR0 = *(const float4*)(Bptr0);
    float4 bR1 = *(const float4*)(Bptr1);

    for (int k0 = 0; k0 < 512; k0 += 32) {
        As[ac2 + 0][ar] = aR.x; As[ac2 + 1][ar] = aR.y;
        *(float4*)&Bs[br][bc4] = bR0;
        *(float4*)&Bs[br + 16][bc4] = bR1;
        __syncthreads();

        if (k0 + 32 < 512) {
            aR  = *(const float2*)(Aptr + k0 + 32);
            bR0 = *(const float4*)(Bptr0 + (k0 + 32) * 512);
            bR1 = *(const float4*)(Bptr1 + (k0 + 32) * 512);
        }

        #pragma unroll
        for (int kk = 0; kk < 32; kk++) {
            float a = As[kk][ty];
            float4 bb = *(const float4*)&Bs[kk][tx * 4];
            acc[0] += a * bb.x; acc[1] += a * bb.y;
            acc[2] += a * bb.z; acc[3] += a * bb.w;
        }
        __syncthreads();
    }

    int m = m0 + ty;
    #pragma unroll
    for (int j = 0; j < 4; j++) {
        int n = n0 + tx * 4 + j;
        C[m * 512 + n] = acc[j] + bias[n];
    }
}

// ---------------------------------------------------------------------------
extern "C" void kernel_launch(void* const* d_in, const int* in_sizes, int n_in,
                              void* d_out, int out_size, void* d_ws, size_t ws_size,
                              hipStream_t stream)
{
    const float* x_q  = (const float*)d_in[0];
    const float* x_k  = (const float*)d_in[1];
    const float* x_v  = (const float*)d_in[2];
    const float* mask = (const float*)d_in[3];
    const float* Wq   = (const float*)d_in[4];
    const float* bq   = (const float*)d_in[5];
    const float* Wk   = (const float*)d_in[6];
    const float* bk   = (const float*)d_in[7];
    const float* Wv   = (const float*)d_in[8];
    const float* bv   = (const float*)d_in[9];
    const float* Wo   = (const float*)d_in[10];
    const float* bo   = (const float*)d_in[11];
    const float* theta= (const float*)d_in[12];
    const float* phi  = (const float*)d_in[13];
    const float* Wre  = (const float*)d_in[14];
    const float* Wim  = (const float*)d_in[15];
    const float* rb   = (const float*)d_in[16];

    float* ws = (float*)d_ws;
    float*  q_ws    = ws;                       // 262144 f
    float*  kT_ws   = ws + 262144;              // 262144 f (b,h,d,t)
    float2* u_ws    = (float2*)(ws + 524288);   // 262144 float2
    float*  rnn_o   = ws + 1048576;             // 262144 f

    float* out_o  = (float*)d_out;              // (2,256,512)
    float* attn_o = out_o + NB * NL * DM;       // (2,8,256,256)

    qkv_gemm<<<dim3(8, 16, 3), 256, 0, stream>>>(
        x_q, x_k, x_v, Wq, Wk, Wv, bq, bk, bv, Wre, Wim,
        q_ws, kT_ws, u_ws);

    rnn_kernel<<<dim3(512), 256, 0, stream>>>(
        q_ws, kT_ws, mask, attn_o, u_ws, theta, phi, rb, rnn_o);

    out_gemm<<<dim3(8, 32), 256, 0, stream>>>(rnn_o, Wo, bo, out_o);
}